// Round 16
// baseline (86.315 us; speedup 1.0000x reference)
//
#include <hip/hip_runtime.h>
#include <math.h>

typedef float    f32x4  __attribute__((ext_vector_type(4)));
typedef __bf16   bf16x8 __attribute__((ext_vector_type(8)));
typedef _Float16 half8  __attribute__((ext_vector_type(8)));
typedef unsigned short ushort_t;
typedef unsigned short ushort8 __attribute__((ext_vector_type(8)));

#define NTOK  4096   // H*W
#define CD    512    // C
#define DD    64     // D
#define BQ    256    // attn query tile (4 waves x 64 rows)
#define BK    64     // key tile
#define KSTR  72     // K/V LDS row stride (elems)
#define PSTR  68     // P LDS row stride
#define NROWS 16384  // B*NTOK
#define LOG2E 1.4426950408889634f

#define MFMAH(a, b, c) __builtin_amdgcn_mfma_f32_16x16x32_f16((a), (b), (c), 0, 0, 0)
#define MFMAB(a, b, c) __builtin_amdgcn_mfma_f32_16x16x32_bf16((a), (b), (c), 0, 0, 0)
#define EXP2(x) __builtin_amdgcn_exp2f(x)

static __device__ __forceinline__ ushort_t f2h(float f) {
    union { _Float16 h; ushort_t u; } a; a.h = (_Float16)f; return a.u;
}
static __device__ __forceinline__ ushort_t f2bf(float f) {
    union { __bf16 h; ushort_t u; } a; a.h = (__bf16)f; return a.u;
}

// ---------------------------------------------------------------------------
// Kernel 0: weight prep (unchanged). All fp16: wqk[col][k] (q=0-63
// log2e-scaled, k=64-127), wv_t[d][k], woT[c][d].
// ---------------------------------------------------------------------------
__global__ __launch_bounds__(256) void wprep_kernel(
    const float* __restrict__ Wq, const float* __restrict__ Wk,
    const float* __restrict__ Wv, const float* __restrict__ Wo,
    ushort_t* __restrict__ wqk, ushort_t* __restrict__ wv_t,
    ushort_t* __restrict__ woT)
{
    const int idx = blockIdx.x * 256 + threadIdx.x;   // 0 .. 131071
    if (idx < 192*512) {
        const int col = idx >> 9;                     // 0..191
        const int k   = idx & 511;
        const float* W = (col < 64) ? Wq : (col < 128 ? Wk : Wv);
        const int c = col & 63;
        float wv = W[(size_t)k*DD + c];
        if (col < 64) wv *= LOG2E;    // q scaled: scores in log2 domain
        if (col < 128) wqk[(size_t)col*CD + k] = f2h(wv);
        else           wv_t[(size_t)(col - 128)*CD + k] = f2h(wv);
    } else {
        const int i = idx - 192*512;                  // 0 .. 32767
        const int c = i >> 6, d = i & 63;
        woT[i] = f2h(Wo[(size_t)d*CD + c]);
    }
}

// ---------------------------------------------------------------------------
// Kernel 1: QKV projection, L2-DIRECT fp16 MFMA GEMM (oproj pattern).
// No LDS staging, no K-loop barriers: A-frags read from x (fp32->fp16 in
// register), B-frags from L2-resident transposed weights (0.4 MB). Wave w
// owns col-frags cf = 3w+j (0-3=q, 4-7=k, 8-11=v) x 2 row-frags. Only the
// V-transpose tile uses LDS (+1 barrier at end).
// ---------------------------------------------------------------------------
__global__ __launch_bounds__(256) void qkv_gemm(
    const float* __restrict__ x,
    const ushort_t* __restrict__ wqk, const ushort_t* __restrict__ wv_t,
    const float* __restrict__ bq, const float* __restrict__ bk,
    const float* __restrict__ bv,
    ushort_t* __restrict__ qf, ushort_t* __restrict__ kf,
    ushort_t* __restrict__ vT)
{
    __shared__ __align__(16) ushort_t vtile[64*40];    // bf16 [d][tok]

    const int tid  = threadIdx.x;
    const int w    = tid >> 6;     // 0..3
    const int lane = tid & 63;
    const int l15  = lane & 15;
    const int l4   = lane >> 4;
    const int r0   = blockIdx.x * 32;

    f32x4 acc[2][3];   // [row-frag][col-frag j]
    #pragma unroll
    for (int rf = 0; rf < 2; ++rf)
        #pragma unroll
        for (int j = 0; j < 3; ++j) acc[rf][j] = (f32x4){0.f,0.f,0.f,0.f};

    // K loop: 16 slices of 32; no barriers -> waves slip, compiler pipelines
    for (int ks = 0; ks < 16; ++ks) {
        const int k0 = 32*ks + 8*l4;
        // A fragments: x rows (fp32) -> fp16 in-register
        half8 af[2];
        #pragma unroll
        for (int rf = 0; rf < 2; ++rf) {
            const float* xp = &x[(size_t)(r0 + rf*16 + l15)*CD + k0];
            const f32x4 a0 = *(const f32x4*)xp;
            const f32x4 a1 = *(const f32x4*)(xp + 4);
            #pragma unroll
            for (int i = 0; i < 4; ++i) {
                af[rf][i]     = (_Float16)a0[i];
                af[rf][i + 4] = (_Float16)a1[i];
            }
        }
        // B fragments direct from L2; 3 col-frags per wave
        #pragma unroll
        for (int j = 0; j < 3; ++j) {
            const int cf = 3*w + j;
            const ushort_t* wp = (cf < 8)
                ? &wqk [(size_t)(16*cf + l15)*CD + k0]
                : &wv_t[(size_t)(16*(cf-8) + l15)*CD + k0];
            const half8 bw = *(const half8*)wp;
            acc[0][j] = MFMAH(af[0], bw, acc[0][j]);
            acc[1][j] = MFMAH(af[1], bw, acc[1][j]);
        }
    }

    // epilogue: bias + relu; q,k -> fp16 global; v -> LDS tile (bf16)
    #pragma unroll
    for (int j = 0; j < 3; ++j) {
        const int cf = 3*w + j;
        const int col16 = cf*16 + l15;
        if (cf < 4) {
            const float bias = bq[col16] * LOG2E;
            #pragma unroll
            for (int rf = 0; rf < 2; ++rf)
                #pragma unroll
                for (int r = 0; r < 4; ++r) {
                    const size_t row = (size_t)(r0 + rf*16 + 4*l4 + r);
                    qf[row*DD + col16] = f2h(fmaxf(acc[rf][j][r] + bias, 0.f));
                }
        } else if (cf < 8) {
            const int kc = col16 - 64;
            const float bias = bk[kc];
            #pragma unroll
            for (int rf = 0; rf < 2; ++rf)
                #pragma unroll
                for (int r = 0; r < 4; ++r) {
                    const size_t row = (size_t)(r0 + rf*16 + 4*l4 + r);
                    kf[row*DD + kc] = f2h(fmaxf(acc[rf][j][r] + bias, 0.f));
                }
        } else {
            const int d = col16 - 128;
            const float bias = bv[d];
            #pragma unroll
            for (int rf = 0; rf < 2; ++rf)
                #pragma unroll
                for (int r = 0; r < 4; ++r)
                    vtile[d*40 + rf*16 + 4*l4 + r] =
                        f2bf(fmaxf(acc[rf][j][r] + bias, 0.f));
        }
    }
    __syncthreads();
    {
        const int d  = tid >> 2;
        const int j8 = (tid & 3) * 8;
        const int bb   = r0 / NTOK;
        const int tok0 = r0 % NTOK;
        ushort8 vv = *(const ushort8*)&vtile[d*40 + j8];
        *(ushort8*)&vT[((size_t)bb*DD + d)*NTOK + tok0 + j8] = vv;
    }
}

// ---------------------------------------------------------------------------
// Kernel 2: flash attention (unchanged r15 champion): 4 waves x 64 q-rows,
// staged K/V with 2 barriers/tile, split-K, XCD-pinned seg, no-max exp2
// softmax, bf16 o_part.
// ---------------------------------------------------------------------------
__global__ __launch_bounds__(256, 2) void attn_kernel(
    const ushort_t* __restrict__ qf, const ushort_t* __restrict__ kf,
    const ushort_t* __restrict__ vT,
    ushort_t* __restrict__ o_part, float* __restrict__ l_part, int nseg)
{
    __shared__ __align__(16) ushort_t kf_s[BK*KSTR];   // fp16 [key][d]
    __shared__ __align__(16) ushort_t vt_s[DD*KSTR];   // bf16 [d][key]
    __shared__ __align__(16) ushort_t p_s [BQ*PSTR];   // bf16, wave-private

    const int tid  = threadIdx.x;
    const int w    = tid >> 6;     // 0..3
    const int lane = tid & 63;
    const int l15  = lane & 15;
    const int l4   = lane >> 4;

    const int p    = blockIdx.x;
    const int seg  = p % nseg;           // at nseg==8: seg pins to one XCD
    const int rest = p / nseg;
    const int qb   = rest & (NTOK/BQ - 1);
    const int b    = rest / (NTOK/BQ);
    const int kv0  = seg * (NTOK / nseg);
    const int tiles = (NTOK / nseg) / BK;

    half8 qfr[4][2];
    #pragma unroll
    for (int u = 0; u < 4; ++u) {
        const size_t qrow = ((size_t)b*NTOK + (size_t)qb*BQ + 64*w + 16*u + l15)*DD;
        #pragma unroll
        for (int s = 0; s < 2; ++s)
            qfr[u][s] = *(const half8*)&qf[qrow + 8*l4 + 32*s];
    }

    f32x4 acc[4][4];
    float l_run[4][4];
    #pragma unroll
    for (int u = 0; u < 4; ++u)
        #pragma unroll
        for (int nt = 0; nt < 4; ++nt) {
            acc[u][nt] = (f32x4){0.f,0.f,0.f,0.f};
            l_run[u][nt] = 0.f;
        }

    const int skey = tid >> 2;          // 0..63
    const int sc   = (tid & 3) * 16;
    const size_t kst = (size_t)b*NTOK*DD + (size_t)skey*DD + sc;
    const size_t vst = (size_t)b*DD*NTOK + (size_t)skey*NTOK + sc;

    ushort8 rgk0, rgk1, rgv0, rgv1;
    rgk0 = *(const ushort8*)&kf[kst + (size_t)kv0*DD];
    rgk1 = *(const ushort8*)&kf[kst + (size_t)kv0*DD + 8];
    rgv0 = *(const ushort8*)&vT[vst + kv0];
    rgv1 = *(const ushort8*)&vT[vst + kv0 + 8];

    for (int t = 0; t < tiles; ++t) {
        __syncthreads();
        *(ushort8*)&kf_s[skey*KSTR + sc]     = rgk0;
        *(ushort8*)&kf_s[skey*KSTR + sc + 8] = rgk1;
        *(ushort8*)&vt_s[skey*KSTR + sc]     = rgv0;
        *(ushort8*)&vt_s[skey*KSTR + sc + 8] = rgv1;
        if (t + 1 < tiles) {
            const size_t ko = (size_t)(kv0 + (t+1)*BK);
            rgk0 = *(const ushort8*)&kf[kst + ko*DD];
            rgk1 = *(const ushort8*)&kf[kst + ko*DD + 8];
            rgv0 = *(const ushort8*)&vT[vst + ko];
            rgv1 = *(const ushort8*)&vT[vst + ko + 8];
        }
        __syncthreads();

        half8 kfr[2][4];
        #pragma unroll
        for (int s = 0; s < 2; ++s)
            #pragma unroll
            for (int nt = 0; nt < 4; ++nt)
                kfr[s][nt] = *(const half8*)&kf_s[(16*nt + l15)*KSTR + 8*l4 + 32*s];

        #pragma unroll
        for (int u = 0; u < 4; ++u) {
            f32x4 sv[4];
            #pragma unroll
            for (int nt = 0; nt < 4; ++nt) sv[nt] = (f32x4){0.f,0.f,0.f,0.f};
            #pragma unroll
            for (int s = 0; s < 2; ++s)
                #pragma unroll
                for (int nt = 0; nt < 4; ++nt)
                    sv[nt] = MFMAH(qfr[u][s], kfr[s][nt], sv[nt]);
            #pragma unroll
            for (int r = 0; r < 4; ++r) {
                float s0 = EXP2(sv[0][r]);
                float s1 = EXP2(sv[1][r]);
                float s2 = EXP2(sv[2][r]);
                float s3 = EXP2(sv[3][r]);
                sv[0][r] = s0; sv[1][r] = s1;
                sv[2][r] = s2; sv[3][r] = s3;
                l_run[u][r] += (s0 + s1) + (s2 + s3);
            }
            #pragma unroll
            for (int nt = 0; nt < 4; ++nt)
                #pragma unroll
                for (int r = 0; r < 4; ++r)
                    p_s[(64*w + 16*u + 4*l4 + r)*PSTR + 16*nt + l15] =
                        f2bf(sv[nt][r]);
        }

        bf16x8 vfr[2][4];
        #pragma unroll
        for (int s = 0; s < 2; ++s)
            #pragma unroll
            for (int nt = 0; nt < 4; ++nt)
                vfr[s][nt] = *(const bf16x8*)&vt_s[(16*nt + l15)*KSTR + 8*l4 + 32*s];
        #pragma unroll
        for (int u = 0; u < 4; ++u) {
            bf16x8 paf0 = *(const bf16x8*)&p_s[(64*w + 16*u + l15)*PSTR + 8*l4];
            bf16x8 paf1 = *(const bf16x8*)&p_s[(64*w + 16*u + l15)*PSTR + 8*l4 + 32];
            #pragma unroll
            for (int nt = 0; nt < 4; ++nt) {
                acc[u][nt] = MFMAB(paf0, vfr[0][nt], acc[u][nt]);
                acc[u][nt] = MFMAB(paf1, vfr[1][nt], acc[u][nt]);
            }
        }
    }

    const size_t prow0 = (size_t)(seg*4 + b)*NTOK + (size_t)qb*BQ + 64*w;
    #pragma unroll
    for (int u = 0; u < 4; ++u)
        #pragma unroll
        for (int r = 0; r < 4; ++r) {
            float ls = l_run[u][r];
            ls += __shfl_xor(ls, 1);
            ls += __shfl_xor(ls, 2);
            ls += __shfl_xor(ls, 4);
            ls += __shfl_xor(ls, 8);
            const size_t row = prow0 + 16*u + 4*l4 + r;
            #pragma unroll
            for (int nt = 0; nt < 4; ++nt)
                o_part[row*DD + 16*nt + l15] = f2bf(acc[u][nt][r]);
            if (l15 == 0) l_part[row] = ls;
        }
}

// ---------------------------------------------------------------------------
// Kernel 3: output projection fp16 MFMA GEMM with fused split-K combine
// (unchanged from r15).
// ---------------------------------------------------------------------------
__global__ __launch_bounds__(256) void oproj_gemm(
    const ushort_t* __restrict__ o_part, const float* __restrict__ l_part,
    const ushort_t* __restrict__ woT, const float* __restrict__ bo,
    float* __restrict__ out, int nseg)
{
    const int tid  = threadIdx.x;
    const int w    = tid >> 6;
    const int lane = tid & 63;
    const int l15  = lane & 15;
    const int l4   = lane >> 4;
    const int r0   = blockIdx.x * 32;
    const int rf   = w & 1;
    const int cg   = w >> 1;

    const int row = r0 + rf*16 + l15;
    float lsum = 0.f;
    for (int s = 0; s < nseg; ++s)
        lsum += l_part[(size_t)s*NROWS + row];
    const float inv = 1.0f / lsum;

    f32x4 acc[16];
    #pragma unroll
    for (int j = 0; j < 16; ++j) acc[j] = (f32x4){0.f,0.f,0.f,0.f};

    #pragma unroll
    for (int ks = 0; ks < 2; ++ks) {
        const int k0 = 8*l4 + 32*ks;
        float ov[8] = {0.f,0.f,0.f,0.f,0.f,0.f,0.f,0.f};
        for (int s = 0; s < nseg; ++s) {
            const bf16x8 a = *(const bf16x8*)
                &o_part[((size_t)s*NROWS + row)*DD + k0];
            #pragma unroll
            for (int i = 0; i < 8; ++i) ov[i] += (float)a[i];
        }
        half8 ah;
        #pragma unroll
        for (int i = 0; i < 8; ++i)
            ah[i] = (_Float16)(ov[i] * inv);
        #pragma unroll
        for (int j = 0; j < 16; ++j) {
            const int cf = cg*16 + j;
            const half8 bfr = *(const half8*)&woT[(size_t)(16*cf + l15)*DD + k0];
            acc[j] = MFMAH(ah, bfr, acc[j]);
        }
    }

    #pragma unroll
    for (int j = 0; j < 16; ++j) {
        const int col  = (cg*16 + j)*16 + l15;
        const float bias = bo[col];
        #pragma unroll
        for (int r = 0; r < 4; ++r)
            out[(size_t)(r0 + rf*16 + 4*l4 + r)*CD + col] =
                fmaxf(acc[j][r] + bias, 0.f);
    }
}

// ---------------------------------------------------------------------------
extern "C" void kernel_launch(void* const* d_in, const int* in_sizes, int n_in,
                              void* d_out, int out_size, void* d_ws, size_t ws_size,
                              hipStream_t stream) {
    const float* x  = (const float*)d_in[0];
    const float* Wq = (const float*)d_in[1];
    const float* bq = (const float*)d_in[2];
    const float* Wk = (const float*)d_in[3];
    const float* bk = (const float*)d_in[4];
    const float* Wv = (const float*)d_in[5];
    const float* bv = (const float*)d_in[6];
    const float* Wo = (const float*)d_in[7];
    const float* bo = (const float*)d_in[8];
    float* out = (float*)d_out;

    ushort_t* u = (ushort_t*)d_ws;
    const size_t SEG = (size_t)NROWS * DD;  // 1048576 elems
    ushort_t* qf  = u;                      // fp16
    ushort_t* kf  = u + SEG;                // fp16
    ushort_t* vT  = u + 2*SEG;              // bf16

    ushort_t* wqk  = u + 3*SEG;             // 128*512 fp16
    ushort_t* wv_t = wqk + 128*512;         // 64*512 fp16
    ushort_t* woT  = wv_t + 64*512;         // 512*64 fp16
    ushort_t* o_part = woT + 512*64;        // bf16 partials

    const size_t base_b  = (3*SEG + 192*512 + 512*64) * sizeof(ushort_t);
    const size_t per_seg = (size_t)NROWS*DD*2 + (size_t)NROWS*4;  // 2MB+64KB
    int nseg = 1;
    if      (ws_size >= base_b + 8*per_seg) nseg = 8;
    else if (ws_size >= base_b + 4*per_seg) nseg = 4;
    else if (ws_size >= base_b + 2*per_seg) nseg = 2;
    float* l_part = (float*)(o_part + (size_t)nseg*NROWS*DD);

    wprep_kernel<<<512, 256, 0, stream>>>(Wq, Wk, Wv, Wo, wqk, wv_t, woT);
    qkv_gemm<<<NROWS/32, 256, 0, stream>>>(x, wqk, wv_t,
                                           bq, bk, bv, qf, kf, vT);
    attn_kernel<<<(NTOK/BQ) * 4 * nseg, 256, 0, stream>>>(
        qf, kf, vT, o_part, l_part, nseg);
    oproj_gemm<<<NROWS/32, 256, 0, stream>>>(o_part, l_part, woT,
                                             bo, out, nseg);
}

// Round 17
// 71.708 us; speedup vs baseline: 1.2037x; 1.2037x over previous
//
#include <hip/hip_runtime.h>
#include <math.h>

typedef float    f32x4  __attribute__((ext_vector_type(4)));
typedef __bf16   bf16x8 __attribute__((ext_vector_type(8)));
typedef _Float16 half8  __attribute__((ext_vector_type(8)));
typedef unsigned short ushort_t;
typedef unsigned short ushort8 __attribute__((ext_vector_type(8)));

#define NTOK  4096   // H*W
#define CD    512    // C
#define DD    64     // D
#define BQ    256    // query tile (4 waves x 64 rows)
#define BK    64     // key tile
#define KSTR  72     // K/V LDS row stride (elems)
#define PSTR  68     // P LDS row stride
#define NROWS 16384  // B*NTOK
#define LOG2E 1.4426950408889634f

#define MFMAH(a, b, c) __builtin_amdgcn_mfma_f32_16x16x32_f16((a), (b), (c), 0, 0, 0)
#define MFMAB(a, b, c) __builtin_amdgcn_mfma_f32_16x16x32_bf16((a), (b), (c), 0, 0, 0)
#define EXP2(x) __builtin_amdgcn_exp2f(x)

static __device__ __forceinline__ ushort_t f2h(float f) {
    union { _Float16 h; ushort_t u; } a; a.h = (_Float16)f; return a.u;
}
static __device__ __forceinline__ ushort_t f2bf(float f) {
    union { __bf16 h; ushort_t u; } a; a.h = (__bf16)f; return a.u;
}

// ---------------------------------------------------------------------------
// Kernel 0: weight prep. All fp16: wqk[col][k] (q=0-63 log2e-scaled,
// k=64-127), wv_t[d][k], woT[c][d].
// ---------------------------------------------------------------------------
__global__ __launch_bounds__(256) void wprep_kernel(
    const float* __restrict__ Wq, const float* __restrict__ Wk,
    const float* __restrict__ Wv, const float* __restrict__ Wo,
    ushort_t* __restrict__ wqk, ushort_t* __restrict__ wv_t,
    ushort_t* __restrict__ woT)
{
    const int idx = blockIdx.x * 256 + threadIdx.x;   // 0 .. 131071
    if (idx < 192*512) {
        const int col = idx >> 9;                     // 0..191
        const int k   = idx & 511;
        const float* W = (col < 64) ? Wq : (col < 128 ? Wk : Wv);
        const int c = col & 63;
        float wv = W[(size_t)k*DD + c];
        if (col < 64) wv *= LOG2E;    // q scaled: scores in log2 domain
        if (col < 128) wqk[(size_t)col*CD + k] = f2h(wv);
        else           wv_t[(size_t)(col - 128)*CD + k] = f2h(wv);
    } else {
        const int i = idx - 192*512;                  // 0 .. 32767
        const int c = i >> 6, d = i & 63;
        woT[i] = f2h(Wo[(size_t)d*CD + c]);
    }
}

// ---------------------------------------------------------------------------
// Kernel 1: QKV projection, fp16 MFMA, LDS-staged (r15 champion).
// ---------------------------------------------------------------------------
__global__ __launch_bounds__(256) void qkv_gemm(
    const float* __restrict__ x,
    const ushort_t* __restrict__ wqk, const ushort_t* __restrict__ wv_t,
    const float* __restrict__ bq, const float* __restrict__ bk,
    const float* __restrict__ bv,
    ushort_t* __restrict__ qf, ushort_t* __restrict__ kf,
    ushort_t* __restrict__ vT)
{
    __shared__ __align__(16) ushort_t xs_s [32*72];    // x fp16
    __shared__ __align__(16) ushort_t wqk_s[128*72];   // fp16
    __shared__ __align__(16) ushort_t wv_s [64*72];    // fp16
    __shared__ __align__(16) ushort_t vtile[64*40];    // bf16 [d][tok]

    const int tid  = threadIdx.x;
    const int w    = tid >> 6;
    const int lane = tid & 63;
    const int l15  = lane & 15;
    const int l4   = lane >> 4;
    const int r0   = blockIdx.x * 32;

    const int rf = w & 1;
    const int cg = w >> 1;

    f32x4 acc[6];
    #pragma unroll
    for (int j = 0; j < 6; ++j) acc[j] = (f32x4){0.f,0.f,0.f,0.f};

    const int xrow = tid >> 3, xk = (tid & 7) * 8;
    const int wcol = tid >> 1, wk = (tid & 1) * 32;
    const int vcol = tid >> 2, vk = (tid & 3) * 16;

    f32x4   px0, px1;
    ushort8 pw[4], pwv[2];

    {
        const float* xp = &x[(size_t)(r0 + xrow)*CD + xk];
        px0 = *(const f32x4*)xp;  px1 = *(const f32x4*)(xp + 4);
        const ushort_t* hp = &wqk[(size_t)wcol*CD + wk];
        #pragma unroll
        for (int i = 0; i < 4; ++i) pw[i] = *(const ushort8*)(hp + 8*i);
        const ushort_t* vp = &wv_t[(size_t)vcol*CD + vk];
        pwv[0] = *(const ushort8*)vp;  pwv[1] = *(const ushort8*)(vp + 8);
    }

    for (int kt = 0; kt < 8; ++kt) {
        __syncthreads();
        {
            ushort8 h8;
            #pragma unroll
            for (int i = 0; i < 8; ++i)
                h8[i] = f2h((i < 4) ? px0[i] : px1[i-4]);
            *(ushort8*)&xs_s[xrow*72 + xk] = h8;
        }
        #pragma unroll
        for (int i = 0; i < 4; ++i)
            *(ushort8*)&wqk_s[wcol*72 + wk + 8*i] = pw[i];
        *(ushort8*)&wv_s[vcol*72 + vk]     = pwv[0];
        *(ushort8*)&wv_s[vcol*72 + vk + 8] = pwv[1];

        if (kt + 1 < 8) {
            const int ko = (kt + 1) * 64;
            const float* xp = &x[(size_t)(r0 + xrow)*CD + ko + xk];
            px0 = *(const f32x4*)xp;  px1 = *(const f32x4*)(xp + 4);
            const ushort_t* hp = &wqk[(size_t)wcol*CD + ko + wk];
            #pragma unroll
            for (int i = 0; i < 4; ++i) pw[i] = *(const ushort8*)(hp + 8*i);
            const ushort_t* vp = &wv_t[(size_t)vcol*CD + ko + vk];
            pwv[0] = *(const ushort8*)vp;  pwv[1] = *(const ushort8*)(vp + 8);
        }
        __syncthreads();

        #pragma unroll
        for (int k32 = 0; k32 < 2; ++k32) {
            const int ao = (rf*16 + l15)*72 + 8*l4 + 32*k32;
            half8 ax = *(const half8*)&xs_s[ao];
            #pragma unroll
            for (int j = 0; j < 6; ++j) {
                const int cf = 6*cg + j;
                if (cf < 8) {
                    const int bo = (16*cf + l15)*72 + 8*l4 + 32*k32;
                    half8 bw = *(const half8*)&wqk_s[bo];
                    acc[j] = MFMAH(ax, bw, acc[j]);
                } else {
                    const int bo = ((cf-8)*16 + l15)*72 + 8*l4 + 32*k32;
                    half8 bw = *(const half8*)&wv_s[bo];
                    acc[j] = MFMAH(ax, bw, acc[j]);
                }
            }
        }
    }

    #pragma unroll
    for (int j = 0; j < 6; ++j) {
        const int cf = 6*cg + j;
        const int col16 = cf*16 + l15;
        if (cf < 4) {
            const float bias = bq[col16] * LOG2E;
            #pragma unroll
            for (int r = 0; r < 4; ++r) {
                const size_t row = (size_t)(r0 + rf*16 + 4*l4 + r);
                qf[row*DD + col16] = f2h(fmaxf(acc[j][r] + bias, 0.f));
            }
        } else if (cf < 8) {
            const int kc = col16 - 64;
            const float bias = bk[kc];
            #pragma unroll
            for (int r = 0; r < 4; ++r) {
                const size_t row = (size_t)(r0 + rf*16 + 4*l4 + r);
                kf[row*DD + kc] = f2h(fmaxf(acc[j][r] + bias, 0.f));
            }
        } else {
            const int d = col16 - 128;
            const float bias = bv[d];
            #pragma unroll
            for (int r = 0; r < 4; ++r)
                vtile[d*40 + rf*16 + 4*l4 + r] =
                    f2bf(fmaxf(acc[j][r] + bias, 0.f));
        }
    }
    __syncthreads();
    {
        const int d  = tid >> 2;
        const int j8 = (tid & 3) * 8;
        const int bb   = r0 / NTOK;
        const int tok0 = r0 % NTOK;
        ushort8 vv = *(const ushort8*)&vtile[d*40 + j8];
        *(ushort8*)&vT[((size_t)bb*DD + d)*NTOK + tok0 + j8] = vv;
    }
}

// ---------------------------------------------------------------------------
// Kernel 2: flash attention (r15 champion): 4 waves x 64 q-rows, staged K/V
// with 2 barriers/tile, split-K, XCD-pinned seg, no-max exp2 softmax,
// bf16 o_part.
// ---------------------------------------------------------------------------
__global__ __launch_bounds__(256, 2) void attn_kernel(
    const ushort_t* __restrict__ qf, const ushort_t* __restrict__ kf,
    const ushort_t* __restrict__ vT,
    ushort_t* __restrict__ o_part, float* __restrict__ l_part, int nseg)
{
    __shared__ __align__(16) ushort_t kf_s[BK*KSTR];   // fp16 [key][d]
    __shared__ __align__(16) ushort_t vt_s[DD*KSTR];   // bf16 [d][key]
    __shared__ __align__(16) ushort_t p_s [BQ*PSTR];   // bf16, wave-private

    const int tid  = threadIdx.x;
    const int w    = tid >> 6;     // 0..3
    const int lane = tid & 63;
    const int l15  = lane & 15;
    const int l4   = lane >> 4;

    const int p    = blockIdx.x;
    const int seg  = p % nseg;           // at nseg==8: seg pins to one XCD
    const int rest = p / nseg;
    const int qb   = rest & (NTOK/BQ - 1);
    const int b    = rest / (NTOK/BQ);
    const int kv0  = seg * (NTOK / nseg);
    const int tiles = (NTOK / nseg) / BK;

    half8 qfr[4][2];
    #pragma unroll
    for (int u = 0; u < 4; ++u) {
        const size_t qrow = ((size_t)b*NTOK + (size_t)qb*BQ + 64*w + 16*u + l15)*DD;
        #pragma unroll
        for (int s = 0; s < 2; ++s)
            qfr[u][s] = *(const half8*)&qf[qrow + 8*l4 + 32*s];
    }

    f32x4 acc[4][4];
    float l_run[4][4];
    #pragma unroll
    for (int u = 0; u < 4; ++u)
        #pragma unroll
        for (int nt = 0; nt < 4; ++nt) {
            acc[u][nt] = (f32x4){0.f,0.f,0.f,0.f};
            l_run[u][nt] = 0.f;
        }

    const int skey = tid >> 2;          // 0..63
    const int sc   = (tid & 3) * 16;
    const size_t kst = (size_t)b*NTOK*DD + (size_t)skey*DD + sc;
    const size_t vst = (size_t)b*DD*NTOK + (size_t)skey*NTOK + sc;

    ushort8 rgk0, rgk1, rgv0, rgv1;
    rgk0 = *(const ushort8*)&kf[kst + (size_t)kv0*DD];
    rgk1 = *(const ushort8*)&kf[kst + (size_t)kv0*DD + 8];
    rgv0 = *(const ushort8*)&vT[vst + kv0];
    rgv1 = *(const ushort8*)&vT[vst + kv0 + 8];

    for (int t = 0; t < tiles; ++t) {
        __syncthreads();
        *(ushort8*)&kf_s[skey*KSTR + sc]     = rgk0;
        *(ushort8*)&kf_s[skey*KSTR + sc + 8] = rgk1;
        *(ushort8*)&vt_s[skey*KSTR + sc]     = rgv0;
        *(ushort8*)&vt_s[skey*KSTR + sc + 8] = rgv1;
        if (t + 1 < tiles) {  // prefetch t+1: full compute phase of cover
            const size_t ko = (size_t)(kv0 + (t+1)*BK);
            rgk0 = *(const ushort8*)&kf[kst + ko*DD];
            rgk1 = *(const ushort8*)&kf[kst + ko*DD + 8];
            rgv0 = *(const ushort8*)&vT[vst + ko];
            rgv1 = *(const ushort8*)&vT[vst + ko + 8];
        }
        __syncthreads();

        half8 kfr[2][4];
        #pragma unroll
        for (int s = 0; s < 2; ++s)
            #pragma unroll
            for (int nt = 0; nt < 4; ++nt)
                kfr[s][nt] = *(const half8*)&kf_s[(16*nt + l15)*KSTR + 8*l4 + 32*s];

        #pragma unroll
        for (int u = 0; u < 4; ++u) {
            f32x4 sv[4];
            #pragma unroll
            for (int nt = 0; nt < 4; ++nt) sv[nt] = (f32x4){0.f,0.f,0.f,0.f};
            #pragma unroll
            for (int s = 0; s < 2; ++s)
                #pragma unroll
                for (int nt = 0; nt < 4; ++nt)
                    sv[nt] = MFMAH(qfr[u][s], kfr[s][nt], sv[nt]);
            #pragma unroll
            for (int r = 0; r < 4; ++r) {
                float s0 = EXP2(sv[0][r]);
                float s1 = EXP2(sv[1][r]);
                float s2 = EXP2(sv[2][r]);
                float s3 = EXP2(sv[3][r]);
                sv[0][r] = s0; sv[1][r] = s1;
                sv[2][r] = s2; sv[3][r] = s3;
                l_run[u][r] += (s0 + s1) + (s2 + s3);
            }
            #pragma unroll
            for (int nt = 0; nt < 4; ++nt)
                #pragma unroll
                for (int r = 0; r < 4; ++r)
                    p_s[(64*w + 16*u + 4*l4 + r)*PSTR + 16*nt + l15] =
                        f2bf(sv[nt][r]);
        }

        bf16x8 vfr[2][4];
        #pragma unroll
        for (int s = 0; s < 2; ++s)
            #pragma unroll
            for (int nt = 0; nt < 4; ++nt)
                vfr[s][nt] = *(const bf16x8*)&vt_s[(16*nt + l15)*KSTR + 8*l4 + 32*s];
        #pragma unroll
        for (int u = 0; u < 4; ++u) {
            bf16x8 paf0 = *(const bf16x8*)&p_s[(64*w + 16*u + l15)*PSTR + 8*l4];
            bf16x8 paf1 = *(const bf16x8*)&p_s[(64*w + 16*u + l15)*PSTR + 8*l4 + 32];
            #pragma unroll
            for (int nt = 0; nt < 4; ++nt) {
                acc[u][nt] = MFMAB(paf0, vfr[0][nt], acc[u][nt]);
                acc[u][nt] = MFMAB(paf1, vfr[1][nt], acc[u][nt]);
            }
        }
    }

    // epilogue: butterfly row-sum, bf16 unnormalized partials + f32 l
    const size_t prow0 = (size_t)(seg*4 + b)*NTOK + (size_t)qb*BQ + 64*w;
    #pragma unroll
    for (int u = 0; u < 4; ++u)
        #pragma unroll
        for (int r = 0; r < 4; ++r) {
            float ls = l_run[u][r];
            ls += __shfl_xor(ls, 1);
            ls += __shfl_xor(ls, 2);
            ls += __shfl_xor(ls, 4);
            ls += __shfl_xor(ls, 8);
            const size_t row = prow0 + 16*u + 4*l4 + r;
            #pragma unroll
            for (int nt = 0; nt < 4; ++nt)
                o_part[row*DD + 16*nt + l15] = f2bf(acc[u][nt][r]);
            if (l15 == 0) l_part[row] = ls;
        }
}

// ---------------------------------------------------------------------------
// Kernel 3: output projection fp16 MFMA GEMM with fused split-K combine
// (r15 champion).
// ---------------------------------------------------------------------------
__global__ __launch_bounds__(256) void oproj_gemm(
    const ushort_t* __restrict__ o_part, const float* __restrict__ l_part,
    const ushort_t* __restrict__ woT, const float* __restrict__ bo,
    float* __restrict__ out, int nseg)
{
    const int tid  = threadIdx.x;
    const int w    = tid >> 6;
    const int lane = tid & 63;
    const int l15  = lane & 15;
    const int l4   = lane >> 4;
    const int r0   = blockIdx.x * 32;
    const int rf   = w & 1;
    const int cg   = w >> 1;

    const int row = r0 + rf*16 + l15;
    float lsum = 0.f;
    for (int s = 0; s < nseg; ++s)
        lsum += l_part[(size_t)s*NROWS + row];
    const float inv = 1.0f / lsum;

    f32x4 acc[16];
    #pragma unroll
    for (int j = 0; j < 16; ++j) acc[j] = (f32x4){0.f,0.f,0.f,0.f};

    #pragma unroll
    for (int ks = 0; ks < 2; ++ks) {
        const int k0 = 8*l4 + 32*ks;
        float ov[8] = {0.f,0.f,0.f,0.f,0.f,0.f,0.f,0.f};
        for (int s = 0; s < nseg; ++s) {
            const bf16x8 a = *(const bf16x8*)
                &o_part[((size_t)s*NROWS + row)*DD + k0];
            #pragma unroll
            for (int i = 0; i < 8; ++i) ov[i] += (float)a[i];
        }
        half8 ah;
        #pragma unroll
        for (int i = 0; i < 8; ++i)
            ah[i] = (_Float16)(ov[i] * inv);
        #pragma unroll
        for (int j = 0; j < 16; ++j) {
            const int cf = cg*16 + j;
            const half8 bfr = *(const half8*)&woT[(size_t)(16*cf + l15)*DD + k0];
            acc[j] = MFMAH(ah, bfr, acc[j]);
        }
    }

    #pragma unroll
    for (int j = 0; j < 16; ++j) {
        const int col  = (cg*16 + j)*16 + l15;
        const float bias = bo[col];
        #pragma unroll
        for (int r = 0; r < 4; ++r)
            out[(size_t)(r0 + rf*16 + 4*l4 + r)*CD + col] =
                fmaxf(acc[j][r] + bias, 0.f);
    }
}

// ---------------------------------------------------------------------------
extern "C" void kernel_launch(void* const* d_in, const int* in_sizes, int n_in,
                              void* d_out, int out_size, void* d_ws, size_t ws_size,
                              hipStream_t stream) {
    const float* x  = (const float*)d_in[0];
    const float* Wq = (const float*)d_in[1];
    const float* bq = (const float*)d_in[2];
    const float* Wk = (const float*)d_in[3];
    const float* bk = (const float*)d_in[4];
    const float* Wv = (const float*)d_in[5];
    const float* bv = (const float*)d_in[6];
    const float* Wo = (const float*)d_in[7];
    const float* bo = (const float*)d_in[8];
    float* out = (float*)d_out;

    ushort_t* u = (ushort_t*)d_ws;
    const size_t SEG = (size_t)NROWS * DD;  // 1048576 elems
    ushort_t* qf  = u;                      // fp16
    ushort_t* kf  = u + SEG;                // fp16
    ushort_t* vT  = u + 2*SEG;              // bf16

    ushort_t* wqk  = u + 3*SEG;             // 128*512 fp16
    ushort_t* wv_t = wqk + 128*512;         // 64*512 fp16
    ushort_t* woT  = wv_t + 64*512;         // 512*64 fp16
    ushort_t* o_part = woT + 512*64;        // bf16 partials

    const size_t base_b  = (3*SEG + 192*512 + 512*64) * sizeof(ushort_t);
    const size_t per_seg = (size_t)NROWS*DD*2 + (size_t)NROWS*4;  // 2MB+64KB
    int nseg = 1;
    if      (ws_size >= base_b + 8*per_seg) nseg = 8;
    else if (ws_size >= base_b + 4*per_seg) nseg = 4;
    else if (ws_size >= base_b + 2*per_seg) nseg = 2;
    float* l_part = (float*)(o_part + (size_t)nseg*NROWS*DD);

    wprep_kernel<<<512, 256, 0, stream>>>(Wq, Wk, Wv, Wo, wqk, wv_t, woT);
    qkv_gemm<<<NROWS/32, 256, 0, stream>>>(x, wqk, wv_t,
                                           bq, bk, bv, qf, kf, vT);
    attn_kernel<<<(NTOK/BQ) * 4 * nseg, 256, 0, stream>>>(
        qf, kf, vT, o_part, l_part, nseg);
    oproj_gemm<<<NROWS/32, 256, 0, stream>>>(o_part, l_part, woT,
                                             bo, out, nseg);
}